// Round 2
// 428.536 us; speedup vs baseline: 1.0365x; 1.0365x over previous
//
#include <hip/hip_runtime.h>

// D8 fused GELU: isotypic->regular butterfly, gelu, regular->isotypic butterfly.
// B=16, N=1024, C=512. All fp32. Pure streaming: 256MB in + 256MB out, no reuse.
// Nontemporal (cache-bypass) loads/stores — working set (512 MiB) exceeds
// L3 (256 MiB) and no byte is ever re-read, so L2/L3 allocation is waste.
// Fix vs last round: ext_vector elements can't bind to float& — use float[8]
// out-array + subscript assignment (identical codegen).

typedef float f4 __attribute__((ext_vector_type(4)));

#define SQ24 0.3535533906f

__device__ __forceinline__ float gelu_f(float x) {
    // gelu(x) ~= x * sigmoid(1.5957691216*x*(1+0.044715*x^2))  (tanh approx)
    float x2 = x * x;
    float z  = 1.5957691216057308f * x * fmaf(0.044715f, x2, 1.0f);
    // clamp so __expf never overflows to inf (avoids inf/inf NaN path)
    float e  = __expf(fminf(-z, 80.0f));
    return x / (1.0f + e);
}

__device__ __forceinline__ void d8_pointwise8(
    float x0, float x1, float x2, float x3,
    float y0, float y1, float y2, float y3,
    float o[8])
{
    // isotypic_to_regular
    float a = x0 + x1, b = x0 - x1, c = x2 + x3, d = x2 - x3;
    float e = y0 + y1, f = y0 - y1, g = y2 + y3, h = y2 - y3;
    float apc = a + c, amc = a - c, bpd = b + d, bmd = b - d;
    float eph = e + h, emh = e - h, fpg = f + g, fmg = f - g;
    float r0 = SQ24 * (apc + eph);
    float r1 = SQ24 * (amc + fmg);
    float r2 = SQ24 * (apc - eph);
    float r3 = SQ24 * (amc - fmg);
    float r4 = SQ24 * (bpd - fpg);
    float r5 = SQ24 * (bmd - emh);
    float r6 = SQ24 * (bpd + fpg);
    float r7 = SQ24 * (bmd + emh);

    // gelu
    float g0 = gelu_f(r0), g1 = gelu_f(r1), g2 = gelu_f(r2), g3 = gelu_f(r3);
    float g4 = gelu_f(r4), g5 = gelu_f(r5), g6 = gelu_f(r6), g7 = gelu_f(r7);

    // regular_to_isotypic
    float a2 = g0 + g1, b2 = g0 - g1, c2 = g2 + g3, d2 = g2 - g3;
    float e2 = g4 + g5, f2 = g4 - g5, gg = g6 + g7, h2 = g6 - g7;
    float apc2 = a2 + c2, cma = c2 - a2, bpd2 = b2 + d2, bmd2 = b2 - d2;
    float epg = e2 + gg, gme = gg - e2, fph = f2 + h2, fmh = f2 - h2;
    o[0] = SQ24 * (apc2 + epg);
    o[1] = SQ24 * (apc2 - epg);
    o[2] = SQ24 * (bpd2 + fph);
    o[3] = SQ24 * (bpd2 - fph);
    o[4] = SQ24 * (gme - cma);
    o[5] = SQ24 * (bmd2 + fmh);
    o[6] = SQ24 * (bmd2 - fmh);
    o[7] = SQ24 * (gme + cma);
}

__global__ __launch_bounds__(256) void d8_gelu_kernel(
    const f4* __restrict__ xA1, const f4* __restrict__ xA2,
    const f4* __restrict__ xB1, const f4* __restrict__ xB2,
    const f4* __restrict__ x2d, f4* __restrict__ out, int n4)
{
    const int C4 = 128;              // 512 channels / 4 per float4
    int t = blockIdx.x * blockDim.x + threadIdx.x;
    if (t >= n4) return;

    int bn = t >> 7;                 // which (b,n) row
    int c4 = t & (C4 - 1);
    size_t b2d = (size_t)bn * (4 * C4) + c4;   // x_2d is (BN, 4*C) flat

    // streaming loads — bypass cache allocation (read exactly once)
    f4 a0 = __builtin_nontemporal_load(xA1 + t);
    f4 a1 = __builtin_nontemporal_load(xA2 + t);
    f4 a2 = __builtin_nontemporal_load(xB1 + t);
    f4 a3 = __builtin_nontemporal_load(xB2 + t);
    const f4* p2d = x2d + b2d;
    f4 b0 = __builtin_nontemporal_load(p2d);
    f4 b1 = __builtin_nontemporal_load(p2d + C4);
    f4 b2 = __builtin_nontemporal_load(p2d + 2 * C4);
    f4 b3 = __builtin_nontemporal_load(p2d + 3 * C4);

    f4 o0, o1, o2, o3, o4, o5, o6, o7;
    #pragma unroll
    for (int i = 0; i < 4; ++i) {
        float r[8];
        d8_pointwise8(a0[i], a1[i], a2[i], a3[i],
                      b0[i], b1[i], b2[i], b3[i], r);
        o0[i] = r[0]; o1[i] = r[1]; o2[i] = r[2]; o3[i] = r[3];
        o4[i] = r[4]; o5[i] = r[5]; o6[i] = r[6]; o7[i] = r[7];
    }

    size_t NT = (size_t)n4;
    // streaming stores — never re-read, bypass L2/L3 allocation
    __builtin_nontemporal_store(o0, out + t);              // iso0
    __builtin_nontemporal_store(o1, out + t + NT);         // iso1
    __builtin_nontemporal_store(o2, out + t + 2 * NT);     // iso2
    __builtin_nontemporal_store(o3, out + t + 3 * NT);     // iso3
    f4* ob = out + 4 * NT + b2d;     // y_2d region, same (BN, 4*C) layout
    __builtin_nontemporal_store(o4, ob);
    __builtin_nontemporal_store(o5, ob + C4);
    __builtin_nontemporal_store(o6, ob + 2 * C4);
    __builtin_nontemporal_store(o7, ob + 3 * C4);
}

extern "C" void kernel_launch(void* const* d_in, const int* in_sizes, int n_in,
                              void* d_out, int out_size, void* d_ws, size_t ws_size,
                              hipStream_t stream) {
    (void)n_in; (void)d_ws; (void)ws_size; (void)out_size;
    const f4* xA1 = (const f4*)d_in[0];
    const f4* xA2 = (const f4*)d_in[1];
    const f4* xB1 = (const f4*)d_in[2];
    const f4* xB2 = (const f4*)d_in[3];
    const f4* x2d = (const f4*)d_in[4];
    f4* out = (f4*)d_out;

    int n  = in_sizes[0];        // B*N*C = 8,388,608
    int n4 = n / 4;              // float4 groups per stream = 2,097,152

    int block = 256;
    int grid  = (n4 + block - 1) / block;   // 8192 blocks
    d8_gelu_kernel<<<grid, block, 0, stream>>>(xA1, xA2, xB1, xB2, x2d, out, n4);
}